// Round 1
// baseline (327.253 us; speedup 1.0000x reference)
//
#include <hip/hip_runtime.h>

#define HW 4096
#define CC 128
#define NB 4

typedef __bf16 bf16x8 __attribute__((ext_vector_type(8)));
typedef float floatx4 __attribute__((ext_vector_type(4)));

// ---------------------------------------------------------------------------
// Projection: q[n,d,i] = sum_c wq[d,c] x[n,c,i] + bq[d]   (same for k, v)
// Outputs: qb, kb as [N][HW][C] bf16 (pixel-major), vb as [N][C][HW] bf16.
// Grid: 256 blocks (n = blk>>6, i0 = (blk&63)*64), 256 threads.
// ---------------------------------------------------------------------------
__global__ __launch_bounds__(256) void proj_kernel(
    const float* __restrict__ x,
    const float* __restrict__ wq, const float* __restrict__ bq,
    const float* __restrict__ wk, const float* __restrict__ bk,
    const float* __restrict__ wv, const float* __restrict__ bv,
    __bf16* __restrict__ qb, __bf16* __restrict__ kb, __bf16* __restrict__ vb)
{
    __shared__ __bf16 Xt[64][136];   // x^T tile, stride 136 (2-way banks = free)

    const int n  = blockIdx.x >> 6;
    const int i0 = (blockIdx.x & 63) << 6;
    const int t  = threadIdx.x;

    const float* xb = x + (size_t)n * CC * HW;

    // load x tile [128 c][64 i] coalesced, transpose to Xt[i][c] as bf16
#pragma unroll 4
    for (int p = 0; p < 32; ++p) {
        int c  = p * 4 + (t >> 6);
        int il = t & 63;
        float v = xb[(size_t)c * HW + i0 + il];
        Xt[il][c] = (__bf16)v;
    }
    __syncthreads();

    const int w    = t >> 6;
    const int lane = t & 63;
    const int l16  = lane & 15;
    const int quad = lane >> 4;

    // A-fragments for this wave's 16 pixels: A[m=l16][k=quad*8+j], k-steps of 32
    bf16x8 afrag[4];
#pragma unroll
    for (int ks = 0; ks < 4; ++ks)
        afrag[ks] = *reinterpret_cast<const bf16x8*>(&Xt[w * 16 + l16][ks * 32 + quad * 8]);

    const float* Ws[3] = {wq, wk, wv};
    const float* Bs[3] = {bq, bk, bv};

#pragma unroll
    for (int m = 0; m < 3; ++m) {
        const float* Wm = Ws[m];
        const float* Bm = Bs[m];
#pragma unroll
        for (int h = 0; h < 8; ++h) {
            int d = h * 16 + l16;
            floatx4 acc = {0.f, 0.f, 0.f, 0.f};
#pragma unroll
            for (int ks = 0; ks < 4; ++ks) {
                // B[k=c][n=d] = Wm[d][c]: 8 consecutive c, fixed d
                const float* wp = Wm + (size_t)d * CC + ks * 32 + quad * 8;
                bf16x8 bfrag;
#pragma unroll
                for (int jj = 0; jj < 8; ++jj) bfrag[jj] = (__bf16)wp[jj];
                acc = __builtin_amdgcn_mfma_f32_16x16x32_bf16(afrag[ks], bfrag, acc, 0, 0, 0);
            }
            float bias = Bm[d];
            // D[row=pixel=quad*4+r][col=d=l16]
#pragma unroll
            for (int r = 0; r < 4; ++r) {
                int i = i0 + w * 16 + quad * 4 + r;
                __bf16 val = (__bf16)(acc[r] + bias);
                if (m == 0)      qb[(size_t)n * HW * CC + (size_t)i * CC + d] = val;
                else if (m == 1) kb[(size_t)n * HW * CC + (size_t)i * CC + d] = val;
                else             vb[(size_t)n * CC * HW + (size_t)d * HW + i] = val;
            }
        }
    }
}

// ---------------------------------------------------------------------------
// Fused flash attention: per block 64 queries (16/wave), loop all 4096 keys in
// tiles of 64 with online softmax; epilogue out = gamma*O/l + x (fp32).
// Grid: 256 blocks (n = blk>>6, i0 = (blk&63)*64), 256 threads.
// ---------------------------------------------------------------------------
__global__ __launch_bounds__(256) void attn_kernel(
    const __bf16* __restrict__ qb, const __bf16* __restrict__ kb,
    const __bf16* __restrict__ vb,
    const float* __restrict__ x, const float* __restrict__ gamma,
    float* __restrict__ out)
{
    __shared__ float smem[64 * 132];   // 33 KB: P tiles during loop, O^T after

    const int n  = blockIdx.x >> 6;
    const int i0 = (blockIdx.x & 63) << 6;
    const int t  = threadIdx.x;
    const int w    = t >> 6;
    const int lane = t & 63;
    const int l16  = lane & 15;
    const int quad = lane >> 4;

    // wave-private P tile: 16 rows x 72 bf16 (stride 144 B -> 2-way banks)
    __bf16* Pw = reinterpret_cast<__bf16*>(smem) + w * (16 * 72);

    // Q A-fragments pinned in registers for the whole j loop
    const __bf16* qrow = qb + ((size_t)n * HW + i0 + w * 16 + l16) * CC;
    bf16x8 qfrag[4];
#pragma unroll
    for (int ks = 0; ks < 4; ++ks)
        qfrag[ks] = *reinterpret_cast<const bf16x8*>(qrow + ks * 32 + quad * 8);

    float m_i[4], l_i[4];
    floatx4 o_acc[8];
#pragma unroll
    for (int r = 0; r < 4; ++r) { m_i[r] = -1e30f; l_i[r] = 0.f; }
#pragma unroll
    for (int h = 0; h < 8; ++h) o_acc[h] = (floatx4){0.f, 0.f, 0.f, 0.f};

    const __bf16* kbase = kb + (size_t)n * HW * CC;
    const __bf16* vbase = vb + (size_t)n * CC * HW;

    for (int j0 = 0; j0 < HW; j0 += 64) {
        // ---- S = Q^T K on a 16x64 subtile (4 j-subtiles g) ----
        floatx4 s[4];
#pragma unroll
        for (int g = 0; g < 4; ++g) s[g] = (floatx4){0.f, 0.f, 0.f, 0.f};
#pragma unroll
        for (int ks = 0; ks < 4; ++ks) {
#pragma unroll
            for (int g = 0; g < 4; ++g) {
                // B[k=c][n=j] = kb[j][c]: 8 consecutive c, fixed j
                bf16x8 kf = *reinterpret_cast<const bf16x8*>(
                    kbase + (size_t)(j0 + g * 16 + l16) * CC + ks * 32 + quad * 8);
                s[g] = __builtin_amdgcn_mfma_f32_16x16x32_bf16(qfrag[ks], kf, s[g], 0, 0, 0);
            }
        }

        // ---- online softmax (rows quad*4+r live across the quad's 16 lanes) ----
        float rmax[4];
#pragma unroll
        for (int r = 0; r < 4; ++r)
            rmax[r] = fmaxf(fmaxf(s[0][r], s[1][r]), fmaxf(s[2][r], s[3][r]));
#pragma unroll
        for (int off = 1; off < 16; off <<= 1) {
#pragma unroll
            for (int r = 0; r < 4; ++r)
                rmax[r] = fmaxf(rmax[r], __shfl_xor(rmax[r], off, 64));
        }
        float alpha[4];
#pragma unroll
        for (int r = 0; r < 4; ++r) {
            float mn = fmaxf(m_i[r], rmax[r]);
            alpha[r] = __expf(m_i[r] - mn);
            m_i[r] = mn;
        }
#pragma unroll
        for (int g = 0; g < 4; ++g)
#pragma unroll
            for (int r = 0; r < 4; ++r)
                s[g][r] = __expf(s[g][r] - m_i[r]);
        float rsum[4];
#pragma unroll
        for (int r = 0; r < 4; ++r)
            rsum[r] = s[0][r] + s[1][r] + s[2][r] + s[3][r];
#pragma unroll
        for (int off = 1; off < 16; off <<= 1) {
#pragma unroll
            for (int r = 0; r < 4; ++r)
                rsum[r] += __shfl_xor(rsum[r], off, 64);
        }
#pragma unroll
        for (int r = 0; r < 4; ++r)
            l_i[r] = l_i[r] * alpha[r] + rsum[r];
#pragma unroll
        for (int h = 0; h < 8; ++h)
#pragma unroll
            for (int r = 0; r < 4; ++r)
                o_acc[h][r] *= alpha[r];

        // ---- P: C/D layout -> LDS -> A-operand layout (wave-private) ----
#pragma unroll
        for (int g = 0; g < 4; ++g)
#pragma unroll
            for (int r = 0; r < 4; ++r)
                Pw[(quad * 4 + r) * 72 + g * 16 + l16] = (__bf16)s[g][r];

        bf16x8 pfrag[2];
#pragma unroll
        for (int tt = 0; tt < 2; ++tt)
            pfrag[tt] = *reinterpret_cast<const bf16x8*>(Pw + l16 * 72 + tt * 32 + quad * 8);

        // ---- O += P V^T : B[k=j][n=c] = vb[c][j]: 8 consecutive j, fixed c ----
#pragma unroll
        for (int tt = 0; tt < 2; ++tt) {
#pragma unroll
            for (int h = 0; h < 8; ++h) {
                bf16x8 vf = *reinterpret_cast<const bf16x8*>(
                    vbase + (size_t)(h * 16 + l16) * HW + j0 + tt * 32 + quad * 8);
                o_acc[h] = __builtin_amdgcn_mfma_f32_16x16x32_bf16(pfrag[tt], vf, o_acc[h], 0, 0, 0);
            }
        }
    }

    // ---- epilogue: O/l -> LDS transpose -> out = gamma*O + x (coalesced) ----
    __syncthreads();   // everyone done with P regions before O^T overwrites
#pragma unroll
    for (int h = 0; h < 8; ++h)
#pragma unroll
        for (int r = 0; r < 4; ++r)
            smem[(w * 16 + quad * 4 + r) * 132 + h * 16 + l16] = o_acc[h][r] / l_i[r];
    __syncthreads();

    float gm = gamma[0];
    const float* xb = x + (size_t)n * CC * HW + i0;
    float* ob = out + (size_t)n * CC * HW + i0;
#pragma unroll 4
    for (int p = 0; p < 32; ++p) {
        int c  = p * 4 + (t >> 6);
        int il = t & 63;
        float val = smem[il * 132 + c];
        ob[(size_t)c * HW + il] = gm * val + xb[(size_t)c * HW + il];
    }
}

extern "C" void kernel_launch(void* const* d_in, const int* in_sizes, int n_in,
                              void* d_out, int out_size, void* d_ws, size_t ws_size,
                              hipStream_t stream) {
    const float* x     = (const float*)d_in[0];
    const float* wq    = (const float*)d_in[1];
    const float* bq    = (const float*)d_in[2];
    const float* wk    = (const float*)d_in[3];
    const float* bk    = (const float*)d_in[4];
    const float* wv    = (const float*)d_in[5];
    const float* bv    = (const float*)d_in[6];
    const float* gamma = (const float*)d_in[7];
    float* out = (float*)d_out;

    __bf16* qb = (__bf16*)d_ws;                       // [N][HW][C]
    __bf16* kb = qb + (size_t)NB * HW * CC;           // [N][HW][C]
    __bf16* vb = kb + (size_t)NB * HW * CC;           // [N][C][HW]

    proj_kernel<<<256, 256, 0, stream>>>(x, wq, bq, wk, bk, wv, bv, qb, kb, vb);
    attn_kernel<<<256, 256, 0, stream>>>(qb, kb, vb, x, gamma, out);
}